// Round 7
// baseline (889.731 us; speedup 1.0000x reference)
//
#include <hip/hip_runtime.h>

typedef unsigned short ushort_t;
typedef unsigned int uint32;
typedef __attribute__((ext_vector_type(8))) short short8;
typedef __attribute__((ext_vector_type(4))) float f32x4;
typedef __attribute__((ext_vector_type(2))) uint32 uint32x2;

__device__ __forceinline__ ushort_t f2bf(float f) {
  uint32 u = __builtin_bit_cast(uint32, f);
  u = (u + 0x7fffu + ((u >> 16) & 1u)) >> 16;
  return (ushort_t)u;
}

__device__ __forceinline__ float fast_exp2(float x) {
#if __has_builtin(__builtin_amdgcn_exp2f)
  return __builtin_amdgcn_exp2f(x);
#else
  return exp2f(x);
#endif
}

__device__ __forceinline__ uint32 cvt_pk_bf16(float lo, float hi) {
  uint32 r;
  asm("v_cvt_pk_bf16_f32 %0, %1, %2" : "=v"(r) : "v"(lo), "v"(hi));
  return r;
}

__device__ __forceinline__ void gload_lds16(const void* g, void* l) {
  __builtin_amdgcn_global_load_lds(
      (const __attribute__((address_space(1))) void*)g,
      (__attribute__((address_space(3))) void*)l, 16, 0, 0);
}

#define MFMA16(a, b, c) __builtin_amdgcn_mfma_f32_16x16x32_bf16((a), (b), (c), 0, 0, 0)

// ---------------- fused f32 -> bf16 conversion of x, Wq, Wk, Wv ----------------
// wqk: [2048][1024] bf16 (Wq rows then Wk rows); wv separate.
__global__ void cvt_all(const float* __restrict__ x, const float* __restrict__ Wq,
                        const float* __restrict__ Wk, const float* __restrict__ Wv,
                        ushort_t* __restrict__ xb, ushort_t* __restrict__ wqk,
                        ushort_t* __restrict__ wv) {
  int i = blockIdx.x * 256 + threadIdx.x;  // group of 8 elements
  const float* src;
  ushort_t* dst;
  int off;
  if (i < 1048576) {
    src = x; dst = xb; off = i;
  } else if (i < 1048576 + 131072) {
    src = Wq; dst = wqk; off = i - 1048576;
  } else if (i < 1048576 + 262144) {
    src = Wk; dst = wqk + 1048576; off = i - (1048576 + 131072);
  } else {
    src = Wv; dst = wv; off = i - (1048576 + 262144);
  }
  const f32x4* s4 = (const f32x4*)src;
  f32x4 a = s4[2 * off], b = s4[2 * off + 1];
  short8 o;
  o[0] = (short)f2bf(a.x); o[1] = (short)f2bf(a.y); o[2] = (short)f2bf(a.z); o[3] = (short)f2bf(a.w);
  o[4] = (short)f2bf(b.x); o[5] = (short)f2bf(b.y); o[6] = (short)f2bf(b.z); o[7] = (short)f2bf(b.w);
  *(short8*)(dst + 8 * off) = o;
}

// ---------------- mask -> additive bias (log2 domain) ----------------
__global__ void maskbias_kernel(const int* __restrict__ mask, float* __restrict__ bias, int n) {
  int i = blockIdx.x * 256 + threadIdx.x;
  if (i < n) bias[i] = mask[i] ? 0.f : -30000.f;
}

// ---------------- fused Q+K projection GEMM, 2-phase double-buffered ----------------
// A: xb [8192][1024], Bt: wqk [2048][1024]. col<1024 -> Q (scaled), else K.
// out [bh][s][d] bf16.
__global__ __launch_bounds__(256, 3) void gemm_qk(const ushort_t* __restrict__ A,
                                                  const ushort_t* __restrict__ Bt,
                                                  const float* __restrict__ bq,
                                                  const float* __restrict__ bk,
                                                  ushort_t* __restrict__ Qb,
                                                  ushort_t* __restrict__ Kb, float qscale) {
  __shared__ ushort_t As[2][128 * 32];
  __shared__ ushort_t Bs[2][128 * 32];
  const int K = 1024;
  const int tid = threadIdx.x;
  const int w = tid >> 6, l = tid & 63;
  const int wr = w >> 1, wc = w & 1;
  const int lr = l & 15, g = l >> 4;
  const int bm = blockIdx.y * 128, bn = blockIdx.x * 128;
  const bool isq = bn < 1024;

  const char* gA = (const char*)(A + (size_t)(bm + w * 32 + (l >> 2)) * K + (l & 3) * 8);
  const char* gB = (const char*)(Bt + (size_t)(bn + w * 32 + (l >> 2)) * K + (l & 3) * 8);
  const size_t rowstep = (size_t)16 * K * 2;

  f32x4 acc[4][4] = {};

  auto stage = [&](int buf, int k0) {
    char* dA = (char*)&As[buf][0] + w * 2048;
    char* dB = (char*)&Bs[buf][0] + w * 2048;
    const char* sA = gA + (size_t)k0 * 2;
    const char* sB = gB + (size_t)k0 * 2;
    gload_lds16(sA, dA);
    gload_lds16(sA + rowstep, dA + 1024);
    gload_lds16(sB, dB);
    gload_lds16(sB + rowstep, dB + 1024);
  };

  stage(0, 0);
  __syncthreads();

  const int nk = K >> 5;
  for (int kk = 0; kk < nk; kk++) {
    const int cur = kk & 1;
    if (kk + 1 < nk) stage(cur ^ 1, (kk + 1) << 5);
    short8 af[4], bf[4];
#pragma unroll
    for (int fm = 0; fm < 4; fm++)
      af[fm] = *(const short8*)(&As[cur][(wr * 64 + fm * 16 + lr) * 32 + g * 8]);
#pragma unroll
    for (int fn = 0; fn < 4; fn++)
      bf[fn] = *(const short8*)(&Bs[cur][(wc * 64 + fn * 16 + lr) * 32 + g * 8]);
#pragma unroll
    for (int fm = 0; fm < 4; fm++)
#pragma unroll
      for (int fn = 0; fn < 4; fn++) acc[fm][fn] = MFMA16(af[fm], bf[fn], acc[fm][fn]);
    __syncthreads();
  }

  const float* bias = isq ? bq : bk;
  ushort_t* C = isq ? Qb : Kb;
  const float scale = isq ? qscale : 1.0f;
#pragma unroll
  for (int fn = 0; fn < 4; fn++) {
    int col = bn + wc * 64 + fn * 16 + lr;
    int colh = col & 1023;
    float bv = bias[colh];
    int h = colh >> 6, d = colh & 63;
#pragma unroll
    for (int fm = 0; fm < 4; fm++) {
      int rowb = bm + wr * 64 + fm * 16 + g * 4;
#pragma unroll
      for (int j = 0; j < 4; j++) {
        int row = rowb + j;
        int b = row >> 11, s = row & 2047;
        float v = (acc[fm][fn][j] + bv) * scale;
        C[((size_t)(b * 16 + h) * 2048 + s) * 64 + d] = f2bf(v);
      }
    }
  }
}

// ---------------- V^T GEMM (swapped operands), 2-phase double-buffered ----------------
// C[m,n] = sum_k A[m,k]*Bt[n,k]; out row-major [M=1024][N=8192], bias per row.
__global__ __launch_bounds__(256, 3) void gemm_v(const ushort_t* __restrict__ A,
                                                 const ushort_t* __restrict__ Bt,
                                                 const float* __restrict__ bias,
                                                 ushort_t* __restrict__ C, int M, int N, int K) {
  __shared__ ushort_t As[2][128 * 32];
  __shared__ ushort_t Bs[2][128 * 32];
  const int tid = threadIdx.x;
  const int w = tid >> 6, l = tid & 63;
  const int wr = w >> 1, wc = w & 1;
  const int lr = l & 15, g = l >> 4;
  const int bm = blockIdx.y * 128, bn = blockIdx.x * 128;

  const char* gA = (const char*)(A + (size_t)(bm + w * 32 + (l >> 2)) * K + (l & 3) * 8);
  const char* gB = (const char*)(Bt + (size_t)(bn + w * 32 + (l >> 2)) * K + (l & 3) * 8);
  const size_t rowstep = (size_t)16 * K * 2;

  f32x4 acc[4][4] = {};

  auto stage = [&](int buf, int k0) {
    char* dA = (char*)&As[buf][0] + w * 2048;
    char* dB = (char*)&Bs[buf][0] + w * 2048;
    const char* sA = gA + (size_t)k0 * 2;
    const char* sB = gB + (size_t)k0 * 2;
    gload_lds16(sA, dA);
    gload_lds16(sA + rowstep, dA + 1024);
    gload_lds16(sB, dB);
    gload_lds16(sB + rowstep, dB + 1024);
  };

  stage(0, 0);
  __syncthreads();

  const int nk = K >> 5;
  for (int kk = 0; kk < nk; kk++) {
    const int cur = kk & 1;
    if (kk + 1 < nk) stage(cur ^ 1, (kk + 1) << 5);
    short8 af[4], bf[4];
#pragma unroll
    for (int fm = 0; fm < 4; fm++)
      af[fm] = *(const short8*)(&As[cur][(wr * 64 + fm * 16 + lr) * 32 + g * 8]);
#pragma unroll
    for (int fn = 0; fn < 4; fn++)
      bf[fn] = *(const short8*)(&Bs[cur][(wc * 64 + fn * 16 + lr) * 32 + g * 8]);
#pragma unroll
    for (int fm = 0; fm < 4; fm++)
#pragma unroll
      for (int fn = 0; fn < 4; fn++) acc[fm][fn] = MFMA16(af[fm], bf[fn], acc[fm][fn]);
    __syncthreads();
  }

#pragma unroll
  for (int fm = 0; fm < 4; fm++) {
#pragma unroll
    for (int j = 0; j < 4; j++) {
      int row = bm + wr * 64 + fm * 16 + g * 4 + j;
      float bv = bias[row];
#pragma unroll
      for (int fn = 0; fn < 4; fn++) {
        int col = bn + wc * 64 + fn * 16 + lr;
        C[(size_t)row * N + col] = f2bf(acc[fm][fn][j] + bv);
      }
    }
  }
}

// ---------------- flash attention + mean over q ----------------
// Q: [bh][s][d] bf16 pre-scaled by log2(e)/8 (log2-domain scores)
// K: [bh][s][d] bf16.  Vt: [h*64+d][b*2048+s] bf16.  mbias: [b][s] f32 additive.
__global__ __launch_bounds__(256, 4) void attn_kernel(const ushort_t* __restrict__ Qb,
                                                      const ushort_t* __restrict__ Kb,
                                                      const ushort_t* __restrict__ Vt,
                                                      const float* __restrict__ mbias,
                                                      float* __restrict__ meanO) {
  __shared__ ushort_t Ks[2][64 * 64];
  __shared__ ushort_t Vs[2][64 * 64];
  __shared__ ushort_t Ps[4][16 * 64];

  const int tid = threadIdx.x;
  const int w = tid >> 6, l = tid & 63;
  const int g = l >> 4, qi = l & 15;
  const int xr = qi & 7;
  const int qblk = blockIdx.x, bh = blockIdx.y;
  const int b = bh >> 4, h = bh & 15;
  const int q0 = qblk * 128 + w * 32;

  // Q fragments for 2 sub-tiles of 16 q-rows
  short8 qf[2][2];
#pragma unroll
  for (int qh = 0; qh < 2; qh++) {
    const ushort_t* qp = Qb + ((size_t)bh * 2048 + q0 + qh * 16 + qi) * 64 + g * 8;
    qf[qh][0] = *(const short8*)qp;
    qf[qh][1] = *(const short8*)(qp + 32);
  }

  // staging source pointers (pre-swizzled chunk so linear LDS dest = swizzled layout)
  const int srow = l >> 3;
  const int sch = (l & 7) ^ srow;
  const char* gK = (const char*)Kb + ((size_t)bh * 2048 + w * 8 + srow) * 128 + sch * 16;
  const char* gV = (const char*)Vt +
                   (((size_t)(h * 64 + w * 8 + srow)) * 8192 + (size_t)b * 2048) * 2 + sch * 16;
  const float* bbase = mbias + b * 2048 + g * 4;

  auto stage = [&](int buf, int t) {
    const char* sK = gK + (size_t)t * (64 * 128);
    const char* sV = gV + (size_t)t * 128;
    char* dK = (char*)&Ks[buf][0] + w * 1024;
    char* dV = (char*)&Vs[buf][0] + w * 1024;
    gload_lds16(sK, dK);
    gload_lds16(sK + 32 * 128, dK + 4096);
    gload_lds16(sV, dV);
    gload_lds16(sV + (size_t)32 * 16384, dV + 4096);
  };

  float mrun[2] = {-1e30f, -1e30f}, lsum[2] = {0.f, 0.f};
  f32x4 ot[2][4] = {};

  stage(0, 0);
  __syncthreads();

  for (int t = 0; t < 32; t++) {
    const int cur = t & 1;
    // mask bias (L1-resident, issued early to hide latency)
    f32x4 bvec[4];
#pragma unroll
    for (int fn = 0; fn < 4; fn++) bvec[fn] = *(const f32x4*)(bbase + t * 64 + fn * 16);

    if (t < 31) stage(cur ^ 1, t + 1);

    // K fragments (shared by both q sub-tiles)
    short8 kf[4][2];
#pragma unroll
    for (int fn = 0; fn < 4; fn++) {
      const ushort_t* kr = &Ks[cur][(fn * 16 + qi) * 64];
      kf[fn][0] = *(const short8*)(kr + (g ^ xr) * 8);
      kf[fn][1] = *(const short8*)(kr + ((4 + g) ^ xr) * 8);
    }
    // V fragments (shared by both q sub-tiles)
    short8 vf[2][4];
#pragma unroll
    for (int tt = 0; tt < 2; tt++)
#pragma unroll
      for (int fd = 0; fd < 4; fd++)
        vf[tt][fd] = *(const short8*)(&Vs[cur][(fd * 16 + qi) * 64] + ((tt * 4 + g) ^ xr) * 8);

    char* Pw = (char*)&Ps[w][0];
#pragma unroll
    for (int qh = 0; qh < 2; qh++) {
      f32x4 sc[4];
#pragma unroll
      for (int fn = 0; fn < 4; fn++) {
        f32x4 z = {};
        z = MFMA16(kf[fn][0], qf[qh][0], z);
        z = MFMA16(kf[fn][1], qf[qh][1], z);
        sc[fn] = z;
      }
      float pmax = -1e30f;
#pragma unroll
      for (int fn = 0; fn < 4; fn++)
#pragma unroll
        for (int j = 0; j < 4; j++) {
          float v = sc[fn][j] + bvec[fn][j];
          sc[fn][j] = v;
          pmax = fmaxf(pmax, v);
        }
      pmax = fmaxf(pmax, __shfl_xor(pmax, 16));
      pmax = fmaxf(pmax, __shfl_xor(pmax, 32));
      if (__any(pmax > mrun[qh] + 8.f)) {
        float mnew = fmaxf(mrun[qh], pmax);
        float r = fast_exp2(mrun[qh] - mnew);
        mrun[qh] = mnew;
        lsum[qh] *= r;
#pragma unroll
        for (int fd = 0; fd < 4; fd++) {
          ot[qh][fd][0] *= r; ot[qh][fd][1] *= r; ot[qh][fd][2] *= r; ot[qh][fd][3] *= r;
        }
      }
      const float m = mrun[qh];
      float psum = 0.f;
      uint32 pk[4][2];
#pragma unroll
      for (int fn = 0; fn < 4; fn++) {
        float p0 = fast_exp2(sc[fn][0] - m);
        float p1 = fast_exp2(sc[fn][1] - m);
        float p2 = fast_exp2(sc[fn][2] - m);
        float p3 = fast_exp2(sc[fn][3] - m);
        psum += (p0 + p1) + (p2 + p3);
        pk[fn][0] = cvt_pk_bf16(p0, p1);
        pk[fn][1] = cvt_pk_bf16(p2, p3);
      }
      psum += __shfl_xor(psum, 16);
      psum += __shfl_xor(psum, 32);
      lsum[qh] += psum;

      // write P (bf16) [q][kv] with (q&7) 16B-chunk XOR swizzle, b64 stores
#pragma unroll
      for (int fn = 0; fn < 4; fn++) {
        uint32x2 pv;
        pv.x = pk[fn][0];
        pv.y = pk[fn][1];
        *(uint32x2*)(Pw + ((qi * 128 + fn * 32 + g * 8) ^ (xr << 4))) = pv;
      }

      // PV: O^T[d][q] += V^T[d][kv] * P[kv][q]
#pragma unroll
      for (int tt = 0; tt < 2; tt++) {
        short8 bp = *(const short8*)(Pw + ((qi * 128 + tt * 64 + g * 16) ^ (xr << 4)));
#pragma unroll
        for (int fd = 0; fd < 4; fd++) ot[qh][fd] = MFMA16(vf[tt][fd], bp, ot[qh][fd]);
      }
    }
    __syncthreads();
  }

  float rl0 = 1.0f / lsum[0], rl1 = 1.0f / lsum[1];
#pragma unroll
  for (int fd = 0; fd < 4; fd++)
#pragma unroll
    for (int j = 0; j < 4; j++) {
      float v = ot[0][fd][j] * rl0 + ot[1][fd][j] * rl1;
      v += __shfl_xor(v, 1);
      v += __shfl_xor(v, 2);
      v += __shfl_xor(v, 4);
      v += __shfl_xor(v, 8);
      if (qi == 0) atomicAdd(&meanO[b * 1024 + h * 64 + fd * 16 + g * 4 + j], v);
    }
}

// ---------------- y[b][n] = (meanO[b]/S) . Wo[n] + bo[n] ----------------
__global__ void proj_o(const float* __restrict__ meanO, const float* __restrict__ Wo,
                       const float* __restrict__ bo, float* __restrict__ y) {
  int b = blockIdx.y;
  int t = threadIdx.x;
  int n = blockIdx.x * 64 + (t >> 2);
  int part = t & 3;
  const f32x4* wrow = (const f32x4*)(Wo + (size_t)n * 1024 + part * 256);
  const f32x4* mo = (const f32x4*)(meanO + b * 1024 + part * 256);
  float acc = 0.f;
#pragma unroll 8
  for (int i = 0; i < 64; i++) {
    f32x4 wv = wrow[i], mv = mo[i];
    acc += wv.x * mv.x + wv.y * mv.y + wv.z * mv.z + wv.w * mv.w;
  }
  acc += __shfl_xor(acc, 1);
  acc += __shfl_xor(acc, 2);
  if (part == 0) y[b * 1024 + n] = acc * (1.0f / 2048.0f) + bo[n];
}

// ---------------- tail: normalize, subtract text, MLP, tanh ----------------
__global__ void tail_kernel(const float* __restrict__ y, const float* __restrict__ text,
                            const float* __restrict__ W1, const float* __restrict__ b1,
                            const float* __restrict__ W2, const float* __restrict__ b2,
                            float* __restrict__ out) {
  __shared__ float u[1024];
  __shared__ float hbuf[512];
  __shared__ float red[8];
  int b = blockIdx.x, t = threadIdx.x;
  const float* yb = y + b * 1024;

  float ss = 0.f;
  for (int i = t; i < 1024; i += 256) {
    float v = yb[i];
    ss += v * v;
  }
  for (int m = 1; m < 64; m <<= 1) ss += __shfl_xor(ss, m);
  if ((t & 63) == 0) red[t >> 6] = ss;
  __syncthreads();
  float rn = rsqrtf(red[0] + red[1] + red[2] + red[3]);
  for (int i = t; i < 1024; i += 256) u[i] = yb[i] * rn - text[b * 1024 + i];
  __syncthreads();

  int grp = t >> 2, part = t & 3;
  for (int p = 0; p < 8; p++) {
    int j = p * 64 + grp;
    const f32x4* wr = (const f32x4*)(W1 + (size_t)j * 1024 + part * 256);
    const f32x4* uu = (const f32x4*)(u + part * 256);
    float a = 0.f;
#pragma unroll 8
    for (int i = 0; i < 64; i++) {
      f32x4 wv = wr[i], uv = uu[i];
      a += wv.x * uv.x + wv.y * uv.y + wv.z * uv.z + wv.w * uv.w;
    }
    a += __shfl_xor(a, 1);
    a += __shfl_xor(a, 2);
    if (part == 0) hbuf[j] = fmaxf(a + b1[j], 0.f);
  }
  __syncthreads();

  float s2 = 0.f;
  for (int j = t; j < 512; j += 256) s2 += hbuf[j] * W2[j];
  for (int m = 1; m < 64; m <<= 1) s2 += __shfl_xor(s2, m);
  if ((t & 63) == 0) red[t >> 6] = s2;
  __syncthreads();
  if (t == 0) out[b] = tanhf(red[0] + red[1] + red[2] + red[3] + b2[0]);
}

extern "C" void kernel_launch(void* const* d_in, const int* in_sizes, int n_in, void* d_out,
                              int out_size, void* d_ws, size_t ws_size, hipStream_t stream) {
  (void)in_sizes; (void)n_in; (void)out_size; (void)ws_size;
  const float* x = (const float*)d_in[0];
  const int* mask = (const int*)d_in[1];
  const float* text = (const float*)d_in[2];
  const float* Wq = (const float*)d_in[3];
  const float* bq = (const float*)d_in[4];
  const float* Wk = (const float*)d_in[5];
  const float* bk = (const float*)d_in[6];
  const float* Wv = (const float*)d_in[7];
  const float* bv = (const float*)d_in[8];
  const float* Wo = (const float*)d_in[9];
  const float* bo = (const float*)d_in[10];
  const float* W1 = (const float*)d_in[11];
  const float* b1 = (const float*)d_in[12];
  const float* W2 = (const float*)d_in[13];
  const float* b2 = (const float*)d_in[14];

  char* ws = (char*)d_ws;
  const size_t MB = 1024 * 1024;
  ushort_t* Qb = (ushort_t*)(ws);
  ushort_t* Kb = (ushort_t*)(ws + 16 * MB);
  ushort_t* Vt = (ushort_t*)(ws + 32 * MB);
  ushort_t* xb = (ushort_t*)(ws + 48 * MB);
  ushort_t* wqk = (ushort_t*)(ws + 64 * MB);  // [2048][1024] Wq then Wk
  ushort_t* wvb = (ushort_t*)(ws + 68 * MB);
  float* meanO = (float*)(ws + 70 * MB);
  float* y = (float*)(ws + 70 * MB + 16384);
  float* mbias = (float*)(ws + 70 * MB + 65536);

  cvt_all<<<5632, 256, 0, stream>>>(x, Wq, Wk, Wv, xb, wqk, wvb);
  maskbias_kernel<<<32, 256, 0, stream>>>(mask, mbias, 8192);
  hipMemsetAsync(meanO, 0, 4096 * sizeof(float), stream);

  // Q = x @ Wq^T (scaled by log2(e)/sqrt(D)) and K = x @ Wk^T, fused: [bh][s][d]
  const float qscale = 0.125f * 1.44269504088896f;
  gemm_qk<<<dim3(16, 64), 256, 0, stream>>>(xb, wqk, bq, bk, Qb, Kb, qscale);
  // V^T = Wv @ x^T : row-major [1024][8192]
  gemm_v<<<dim3(64, 8), 256, 0, stream>>>(wvb, xb, bv, Vt, 1024, 8192, 1024);

  attn_kernel<<<dim3(16, 64), 256, 0, stream>>>(Qb, Kb, Vt, mbias, meanO);
  proj_o<<<dim3(16, 4), 256, 0, stream>>>(meanO, Wo, bo, y);
  tail_kernel<<<4, 256, 0, stream>>>(y, text, W1, b1, W2, b2, (float*)d_out);
}

// Round 9
// 401.852 us; speedup vs baseline: 2.2141x; 2.2141x over previous
//
#include <hip/hip_runtime.h>

typedef unsigned short ushort_t;
typedef unsigned int uint32;
typedef __attribute__((ext_vector_type(8))) short short8;
typedef __attribute__((ext_vector_type(4))) float f32x4;

__device__ __forceinline__ ushort_t f2bf(float f) {
  uint32 u = __builtin_bit_cast(uint32, f);
  u = (u + 0x7fffu + ((u >> 16) & 1u)) >> 16;
  return (ushort_t)u;
}

__device__ __forceinline__ float fast_exp2(float x) {
#if __has_builtin(__builtin_amdgcn_exp2f)
  return __builtin_amdgcn_exp2f(x);
#else
  return exp2f(x);
#endif
}

__device__ __forceinline__ void gload_lds16(const void* g, void* l) {
  __builtin_amdgcn_global_load_lds(
      (const __attribute__((address_space(1))) void*)g,
      (__attribute__((address_space(3))) void*)l, 16, 0, 0);
}

#define MFMA16(a, b, c) __builtin_amdgcn_mfma_f32_16x16x32_bf16((a), (b), (c), 0, 0, 0)

// ---------------- fused f32 -> bf16 conversion of x, Wq, Wk, Wv ----------------
__global__ void cvt_all(const float* __restrict__ x, const float* __restrict__ Wq,
                        const float* __restrict__ Wk, const float* __restrict__ Wv,
                        ushort_t* __restrict__ xb, ushort_t* __restrict__ wqk,
                        ushort_t* __restrict__ wv) {
  int i = blockIdx.x * 256 + threadIdx.x;  // group of 8 elements
  const float* src;
  ushort_t* dst;
  int off;
  if (i < 1048576) {
    src = x; dst = xb; off = i;
  } else if (i < 1048576 + 131072) {
    src = Wq; dst = wqk; off = i - 1048576;
  } else if (i < 1048576 + 262144) {
    src = Wk; dst = wqk + 1048576; off = i - (1048576 + 131072);
  } else {
    src = Wv; dst = wv; off = i - (1048576 + 262144);
  }
  const f32x4* s4 = (const f32x4*)src;
  f32x4 a = s4[2 * off], b = s4[2 * off + 1];
  short8 o;
  o[0] = (short)f2bf(a.x); o[1] = (short)f2bf(a.y); o[2] = (short)f2bf(a.z); o[3] = (short)f2bf(a.w);
  o[4] = (short)f2bf(b.x); o[5] = (short)f2bf(b.y); o[6] = (short)f2bf(b.z); o[7] = (short)f2bf(b.w);
  *(short8*)(dst + 8 * off) = o;
}

// ---------------- mask -> additive bias (log2 domain) ----------------
__global__ void maskbias_kernel(const int* __restrict__ mask, float* __restrict__ bias, int n) {
  int i = blockIdx.x * 256 + threadIdx.x;
  if (i < n) bias[i] = mask[i] ? 0.f : -30000.f;
}

// ---------------- fused Q+K projection GEMM, 2-phase double-buffered ----------------
// A: xb [8192][1024], Bt: wqk [2048][1024]. col<1024 -> Q (scaled), else K.
// out [bh][s][d] bf16.
__global__ __launch_bounds__(256, 2) void gemm_qk(const ushort_t* __restrict__ A,
                                                  const ushort_t* __restrict__ Bt,
                                                  const float* __restrict__ bq,
                                                  const float* __restrict__ bk,
                                                  ushort_t* __restrict__ Qb,
                                                  ushort_t* __restrict__ Kb, float qscale) {
  __shared__ ushort_t As[2][128 * 32];
  __shared__ ushort_t Bs[2][128 * 32];
  const int K = 1024;
  const int tid = threadIdx.x;
  const int w = tid >> 6, l = tid & 63;
  const int wr = w >> 1, wc = w & 1;
  const int lr = l & 15, g = l >> 4;
  const int bm = blockIdx.y * 128, bn = blockIdx.x * 128;
  const bool isq = bn < 1024;

  const char* gA = (const char*)(A + (size_t)(bm + w * 32 + (l >> 2)) * K + (l & 3) * 8);
  const char* gB = (const char*)(Bt + (size_t)(bn + w * 32 + (l >> 2)) * K + (l & 3) * 8);
  const size_t rowstep = (size_t)16 * K * 2;

  f32x4 acc[4][4] = {};

  auto stage = [&](int buf, int k0) {
    char* dA = (char*)&As[buf][0] + w * 2048;
    char* dB = (char*)&Bs[buf][0] + w * 2048;
    const char* sA = gA + (size_t)k0 * 2;
    const char* sB = gB + (size_t)k0 * 2;
    gload_lds16(sA, dA);
    gload_lds16(sA + rowstep, dA + 1024);
    gload_lds16(sB, dB);
    gload_lds16(sB + rowstep, dB + 1024);
  };

  stage(0, 0);
  __syncthreads();

  const int nk = K >> 5;
  for (int kk = 0; kk < nk; kk++) {
    const int cur = kk & 1;
    if (kk + 1 < nk) stage(cur ^ 1, (kk + 1) << 5);
    short8 af[4], bf[4];
#pragma unroll
    for (int fm = 0; fm < 4; fm++)
      af[fm] = *(const short8*)(&As[cur][(wr * 64 + fm * 16 + lr) * 32 + g * 8]);
#pragma unroll
    for (int fn = 0; fn < 4; fn++)
      bf[fn] = *(const short8*)(&Bs[cur][(wc * 64 + fn * 16 + lr) * 32 + g * 8]);
#pragma unroll
    for (int fm = 0; fm < 4; fm++)
#pragma unroll
      for (int fn = 0; fn < 4; fn++) acc[fm][fn] = MFMA16(af[fm], bf[fn], acc[fm][fn]);
    __syncthreads();
  }

  const float* bias = isq ? bq : bk;
  ushort_t* C = isq ? Qb : Kb;
  const float scale = isq ? qscale : 1.0f;
#pragma unroll
  for (int fn = 0; fn < 4; fn++) {
    int col = bn + wc * 64 + fn * 16 + lr;
    int colh = col & 1023;
    float bv = bias[colh];
    int h = colh >> 6, d = colh & 63;
#pragma unroll
    for (int fm = 0; fm < 4; fm++) {
      int rowb = bm + wr * 64 + fm * 16 + g * 4;
#pragma unroll
      for (int j = 0; j < 4; j++) {
        int row = rowb + j;
        int b = row >> 11, s = row & 2047;
        float v = (acc[fm][fn][j] + bv) * scale;
        C[((size_t)(b * 16 + h) * 2048 + s) * 64 + d] = f2bf(v);
      }
    }
  }
}

// ---------------- V projection GEMM, f32 output ----------------
// A: xb [8192][1024], Bt: wvb [1024][1024]. C f32 row-major [8192][1024] (= V[b,s,h,d]).
__global__ __launch_bounds__(256, 2) void gemm_vf(const ushort_t* __restrict__ A,
                                                  const ushort_t* __restrict__ Bt,
                                                  const float* __restrict__ bias,
                                                  float* __restrict__ C) {
  __shared__ ushort_t As[2][128 * 32];
  __shared__ ushort_t Bs[2][128 * 32];
  const int K = 1024;
  const int tid = threadIdx.x;
  const int w = tid >> 6, l = tid & 63;
  const int wr = w >> 1, wc = w & 1;
  const int lr = l & 15, g = l >> 4;
  const int bm = blockIdx.y * 128, bn = blockIdx.x * 128;

  const char* gA = (const char*)(A + (size_t)(bm + w * 32 + (l >> 2)) * K + (l & 3) * 8);
  const char* gB = (const char*)(Bt + (size_t)(bn + w * 32 + (l >> 2)) * K + (l & 3) * 8);
  const size_t rowstep = (size_t)16 * K * 2;

  f32x4 acc[4][4] = {};

  auto stage = [&](int buf, int k0) {
    char* dA = (char*)&As[buf][0] + w * 2048;
    char* dB = (char*)&Bs[buf][0] + w * 2048;
    const char* sA = gA + (size_t)k0 * 2;
    const char* sB = gB + (size_t)k0 * 2;
    gload_lds16(sA, dA);
    gload_lds16(sA + rowstep, dA + 1024);
    gload_lds16(sB, dB);
    gload_lds16(sB + rowstep, dB + 1024);
  };

  stage(0, 0);
  __syncthreads();

  const int nk = K >> 5;
  for (int kk = 0; kk < nk; kk++) {
    const int cur = kk & 1;
    if (kk + 1 < nk) stage(cur ^ 1, (kk + 1) << 5);
    short8 af[4], bf[4];
#pragma unroll
    for (int fm = 0; fm < 4; fm++)
      af[fm] = *(const short8*)(&As[cur][(wr * 64 + fm * 16 + lr) * 32 + g * 8]);
#pragma unroll
    for (int fn = 0; fn < 4; fn++)
      bf[fn] = *(const short8*)(&Bs[cur][(wc * 64 + fn * 16 + lr) * 32 + g * 8]);
#pragma unroll
    for (int fm = 0; fm < 4; fm++)
#pragma unroll
      for (int fn = 0; fn < 4; fn++) acc[fm][fn] = MFMA16(af[fm], bf[fn], acc[fm][fn]);
    __syncthreads();
  }

#pragma unroll
  for (int fn = 0; fn < 4; fn++) {
    int col = bn + wc * 64 + fn * 16 + lr;
    float bv = bias[col];
#pragma unroll
    for (int fm = 0; fm < 4; fm++) {
      int rowb = bm + wr * 64 + fm * 16 + g * 4;
#pragma unroll
      for (int j = 0; j < 4; j++) {
        C[(size_t)(rowb + j) * 1024 + col] = acc[fm][fn][j] + bv;
      }
    }
  }
}

// ---------------- pass 1: per-q softmax normalizer c_q = m + log2(sum) ----------------
// Q pre-scaled by log2(e)/8; scores in log2 domain.
__global__ __launch_bounds__(256, 3) void qk_stats(const ushort_t* __restrict__ Qb,
                                                   const ushort_t* __restrict__ Kb,
                                                   const float* __restrict__ mbias,
                                                   float* __restrict__ cq) {
  __shared__ ushort_t Ks[2][64 * 64];
  const int tid = threadIdx.x;
  const int w = tid >> 6, l = tid & 63;
  const int g = l >> 4, qi = l & 15;
  const int xr = qi & 7;
  const int qblk = blockIdx.x, bh = blockIdx.y;
  const int b = bh >> 4;
  const int q0 = qblk * 128 + w * 32;

  short8 qf[2][2];
#pragma unroll
  for (int qh = 0; qh < 2; qh++) {
    const ushort_t* qp = Qb + ((size_t)bh * 2048 + q0 + qh * 16 + qi) * 64 + g * 8;
    qf[qh][0] = *(const short8*)qp;
    qf[qh][1] = *(const short8*)(qp + 32);
  }

  const int srow = l >> 3;
  const int sch = (l & 7) ^ srow;
  const char* gK = (const char*)Kb + ((size_t)bh * 2048 + w * 8 + srow) * 128 + sch * 16;
  const float* bbase = mbias + b * 2048 + g * 4;

  auto stage = [&](int buf, int t) {
    const char* sK = gK + (size_t)t * (64 * 128);
    char* dK = (char*)&Ks[buf][0] + w * 1024;
    gload_lds16(sK, dK);
    gload_lds16(sK + 32 * 128, dK + 4096);
  };

  float mrun[2] = {-1e30f, -1e30f}, lsum[2] = {0.f, 0.f};
  stage(0, 0);
  __syncthreads();

  for (int t = 0; t < 32; t++) {
    const int cur = t & 1;
    f32x4 bvec[4];
#pragma unroll
    for (int fn = 0; fn < 4; fn++) bvec[fn] = *(const f32x4*)(bbase + t * 64 + fn * 16);

    if (t < 31) stage(cur ^ 1, t + 1);

    short8 kf[4][2];
#pragma unroll
    for (int fn = 0; fn < 4; fn++) {
      const ushort_t* kr = &Ks[cur][(fn * 16 + qi) * 64];
      kf[fn][0] = *(const short8*)(kr + (g ^ xr) * 8);
      kf[fn][1] = *(const short8*)(kr + ((4 + g) ^ xr) * 8);
    }

#pragma unroll
    for (int qh = 0; qh < 2; qh++) {
      f32x4 sc[4];
#pragma unroll
      for (int fn = 0; fn < 4; fn++) {
        f32x4 z = {};
        z = MFMA16(kf[fn][0], qf[qh][0], z);
        z = MFMA16(kf[fn][1], qf[qh][1], z);
        sc[fn] = z;
      }
      float pmax = -1e30f;
#pragma unroll
      for (int fn = 0; fn < 4; fn++)
#pragma unroll
        for (int j = 0; j < 4; j++) {
          float v = sc[fn][j] + bvec[fn][j];
          sc[fn][j] = v;
          pmax = fmaxf(pmax, v);
        }
      pmax = fmaxf(pmax, __shfl_xor(pmax, 16));
      pmax = fmaxf(pmax, __shfl_xor(pmax, 32));
      if (__any(pmax > mrun[qh] + 8.f)) {
        float mnew = fmaxf(mrun[qh], pmax);
        lsum[qh] *= fast_exp2(mrun[qh] - mnew);
        mrun[qh] = mnew;
      }
      const float m = mrun[qh];
      float psum = 0.f;
#pragma unroll
      for (int fn = 0; fn < 4; fn++) {
        float p0 = fast_exp2(sc[fn][0] - m);
        float p1 = fast_exp2(sc[fn][1] - m);
        float p2 = fast_exp2(sc[fn][2] - m);
        float p3 = fast_exp2(sc[fn][3] - m);
        psum += (p0 + p1) + (p2 + p3);
      }
      psum += __shfl_xor(psum, 16);
      psum += __shfl_xor(psum, 32);
      lsum[qh] += psum;
    }
    __syncthreads();
  }

#pragma unroll
  for (int qh = 0; qh < 2; qh++)
    if (l < 16) cq[(size_t)bh * 2048 + q0 + qh * 16 + l] = mrun[qh] + __log2f(lsum[qh]);
}

// ---------------- pass 2: w_k = sum_q 2^(s_kq - c_q); meanO += V^T w (f32) ----------------
__global__ __launch_bounds__(256, 2) void wsum_v(const ushort_t* __restrict__ Qb,
                                                 const ushort_t* __restrict__ Kb,
                                                 const float* __restrict__ Vf,
                                                 const float* __restrict__ mbias,
                                                 const float* __restrict__ cq,
                                                 float* __restrict__ meanO) {
  __shared__ ushort_t Qs[2][64 * 64];
  __shared__ float wl[4][64];
  const int tid = threadIdx.x;
  const int w = tid >> 6, l = tid & 63;
  const int g = l >> 4, qi = l & 15;
  const int xr = qi & 7;
  const int kvb = blockIdx.x, bh = blockIdx.y;
  const int b = bh >> 4, h = bh & 15;
  const int kv0 = kvb * 256 + w * 64;  // wave's kv base within bh

  // persistent K fragments for this wave's 64 kv rows
  short8 kf[4][2];
#pragma unroll
  for (int fn = 0; fn < 4; fn++) {
    const ushort_t* kp = Kb + ((size_t)bh * 2048 + kv0 + fn * 16 + qi) * 64 + g * 8;
    kf[fn][0] = *(const short8*)kp;
    kf[fn][1] = *(const short8*)(kp + 32);
  }
  f32x4 bvec[4];
#pragma unroll
  for (int fn = 0; fn < 4; fn++)
    bvec[fn] = *(const f32x4*)(mbias + b * 2048 + kv0 + fn * 16 + g * 4);

  const int srow = l >> 3, sch = (l & 7) ^ srow;
  const char* gQ = (const char*)Qb + ((size_t)bh * 2048 + w * 8 + srow) * 128 + sch * 16;
  auto stageQ = [&](int buf, int t) {
    const char* sQ = gQ + (size_t)t * (64 * 128);
    char* dQ = (char*)&Qs[buf][0] + w * 1024;
    gload_lds16(sQ, dQ);
    gload_lds16(sQ + 32 * 128, dQ + 4096);
  };

  f32x4 acc[4] = {};
  const float* cqb = cq + (size_t)bh * 2048;
  stageQ(0, 0);
  __syncthreads();

  for (int t = 0; t < 32; t++) {
    const int cur = t & 1;
    if (t < 31) stageQ(cur ^ 1, t + 1);
#pragma unroll
    for (int sub = 0; sub < 4; sub++) {
      const ushort_t* qr = &Qs[cur][(sub * 16 + qi) * 64];
      short8 q0f = *(const short8*)(qr + (g ^ xr) * 8);
      short8 q1f = *(const short8*)(qr + ((4 + g) ^ xr) * 8);
      float cv = cqb[t * 64 + sub * 16 + qi];
#pragma unroll
      for (int fn = 0; fn < 4; fn++) {
        f32x4 z = {};
        z = MFMA16(kf[fn][0], q0f, z);
        z = MFMA16(kf[fn][1], q1f, z);
#pragma unroll
        for (int j = 0; j < 4; j++) acc[fn][j] += fast_exp2(z[j] + bvec[fn][j] - cv);
      }
    }
    __syncthreads();
  }

  // reduce over the 16 q-lanes (lane bits 0..3)
#pragma unroll
  for (int msk = 1; msk < 16; msk <<= 1) {
#pragma unroll
    for (int fn = 0; fn < 4; fn++) {
      acc[fn][0] += __shfl_xor(acc[fn][0], msk);
      acc[fn][1] += __shfl_xor(acc[fn][1], msk);
      acc[fn][2] += __shfl_xor(acc[fn][2], msk);
      acc[fn][3] += __shfl_xor(acc[fn][3], msk);
    }
  }
  if (qi == 0) {
#pragma unroll
    for (int fn = 0; fn < 4; fn++)
#pragma unroll
      for (int j = 0; j < 4; j++) wl[w][fn * 16 + g * 4 + j] = acc[fn][j];
  }
  __syncthreads();

  // f32 V contraction: lane l = d
  float od = 0.f;
  const float* vrow = Vf + (size_t)(b * 2048 + kv0) * 1024 + h * 64 + l;
  const float* wp = wl[w];
#pragma unroll 8
  for (int k = 0; k < 64; k++) od += wp[k] * vrow[(size_t)k * 1024];
  atomicAdd(&meanO[b * 1024 + h * 64 + l], od);
}

// ---------------- y[b][n] = (meanO[b]/S) . Wo[n] + bo[n] ----------------
__global__ void proj_o(const float* __restrict__ meanO, const float* __restrict__ Wo,
                       const float* __restrict__ bo, float* __restrict__ y) {
  int b = blockIdx.y;
  int t = threadIdx.x;
  int n = blockIdx.x * 64 + (t >> 2);
  int part = t & 3;
  const f32x4* wrow = (const f32x4*)(Wo + (size_t)n * 1024 + part * 256);
  const f32x4* mo = (const f32x4*)(meanO + b * 1024 + part * 256);
  float acc = 0.f;
#pragma unroll 8
  for (int i = 0; i < 64; i++) {
    f32x4 wv = wrow[i], mv = mo[i];
    acc += wv.x * mv.x + wv.y * mv.y + wv.z * mv.z + wv.w * mv.w;
  }
  acc += __shfl_xor(acc, 1);
  acc += __shfl_xor(acc, 2);
  if (part == 0) y[b * 1024 + n] = acc * (1.0f / 2048.0f) + bo[n];
}

// ---------------- tail: normalize, subtract text, MLP, tanh ----------------
__global__ void tail_kernel(const float* __restrict__ y, const float* __restrict__ text,
                            const float* __restrict__ W1, const float* __restrict__ b1,
                            const float* __restrict__ W2, const float* __restrict__ b2,
                            float* __restrict__ out) {
  __shared__ float u[1024];
  __shared__ float hbuf[512];
  __shared__ float red[8];
  int b = blockIdx.x, t = threadIdx.x;
  const float* yb = y + b * 1024;

  float ss = 0.f;
  for (int i = t; i < 1024; i += 256) {
    float v = yb[i];
    ss += v * v;
  }
  for (int m = 1; m < 64; m <<= 1) ss += __shfl_xor(ss, m);
  if ((t & 63) == 0) red[t >> 6] = ss;
  __syncthreads();
  float rn = rsqrtf(red[0] + red[1] + red[2] + red[3]);
  for (int i = t; i < 1024; i += 256) u[i] = yb[i] * rn - text[b * 1024 + i];
  __syncthreads();

  int grp = t >> 2, part = t & 3;
  for (int p = 0; p < 8; p++) {
    int j = p * 64 + grp;
    const f32x4* wr = (const f32x4*)(W1 + (size_t)j * 1024 + part * 256);
    const f32x4* uu = (const f32x4*)(u + part * 256);
    float a = 0.f;
#pragma unroll 8
    for (int i = 0; i < 64; i++) {
      f32x4 wv = wr[i], uv = uu[i];
      a += wv.x * uv.x + wv.y * uv.y + wv.z * uv.z + wv.w * uv.w;
    }
    a += __shfl_xor(a, 1);
    a += __shfl_xor(a, 2);
    if (part == 0) hbuf[j] = fmaxf(a + b1[j], 0.f);
  }
  __syncthreads();

  float s2 = 0.f;
  for (int j = t; j < 512; j += 256) s2 += hbuf[j] * W2[j];
  for (int m = 1; m < 64; m <<= 1) s2 += __shfl_xor(s2, m);
  if ((t & 63) == 0) red[t >> 6] = s2;
  __syncthreads();
  if (t == 0) out[b] = tanhf(red[0] + red[1] + red[2] + red[3] + b2[0]);
}

extern "C" void kernel_launch(void* const* d_in, const int* in_sizes, int n_in, void* d_out,
                              int out_size, void* d_ws, size_t ws_size, hipStream_t stream) {
  (void)in_sizes; (void)n_in; (void)out_size; (void)ws_size;
  const float* x = (const float*)d_in[0];
  const int* mask = (const int*)d_in[1];
  const float* text = (const float*)d_in[2];
  const float* Wq = (const float*)d_in[3];
  const float* bq = (const float*)d_in[4];
  const float* Wk = (const float*)d_in[5];
  const float* bk = (const float*)d_in[6];
  const float* Wv = (const float*)d_in[7];
  const float* bv = (const float*)d_in[8];
  const float* Wo = (const float*)d_in[9];
  const float* bo = (const float*)d_in[10];
  const float* W1 = (const float*)d_in[11];
  const float* b1 = (const float*)d_in[12];
  const float* W2 = (const float*)d_in[13];
  const float* b2 = (const float*)d_in[14];

  char* ws = (char*)d_ws;
  const size_t MB = 1024 * 1024;
  ushort_t* Qb = (ushort_t*)(ws);             // 16 MB  [bh][s][d] bf16
  ushort_t* Kb = (ushort_t*)(ws + 16 * MB);   // 16 MB  [bh][s][d] bf16
  float* Vf = (float*)(ws + 32 * MB);         // 32 MB  [b*2048+s][h*64+d] f32
  ushort_t* xb = (ushort_t*)(ws + 64 * MB);   // 16 MB
  ushort_t* wqk = (ushort_t*)(ws + 80 * MB);  // 4 MB   [2048][1024] Wq then Wk
  ushort_t* wvb = (ushort_t*)(ws + 84 * MB);  // 2 MB
  float* cq = (float*)(ws + 86 * MB);         // 512 KB [bh][2048]
  float* meanO = (float*)(ws + 87 * MB);      // 16 KB
  float* y = (float*)(ws + 87 * MB + 16384);
  float* mbias = (float*)(ws + 87 * MB + 65536);

  cvt_all<<<5632, 256, 0, stream>>>(x, Wq, Wk, Wv, xb, wqk, wvb);
  maskbias_kernel<<<32, 256, 0, stream>>>(mask, mbias, 8192);
  hipMemsetAsync(meanO, 0, 4096 * sizeof(float), stream);

  // Q = x @ Wq^T (scaled by log2(e)/sqrt(D)) and K = x @ Wk^T, fused: [bh][s][d]
  const float qscale = 0.125f * 1.44269504088896f;
  gemm_qk<<<dim3(16, 64), 256, 0, stream>>>(xb, wqk, bq, bk, Qb, Kb, qscale);
  // V = x @ Wv^T + bv, f32 row-major [8192][1024]
  gemm_vf<<<dim3(8, 64), 256, 0, stream>>>(xb, wvb, bv, Vf);

  qk_stats<<<dim3(16, 64), 256, 0, stream>>>(Qb, Kb, mbias, cq);
  wsum_v<<<dim3(8, 64), 256, 0, stream>>>(Qb, Kb, Vf, mbias, cq, meanO);

  proj_o<<<dim3(16, 4), 256, 0, stream>>>(meanO, Wo, bo, y);
  tail_kernel<<<4, 256, 0, stream>>>(y, text, W1, b1, W2, b2, (float*)d_out);
}

// Round 13
// 358.728 us; speedup vs baseline: 2.4802x; 1.1202x over previous
//
#include <hip/hip_runtime.h>

typedef unsigned short ushort_t;
typedef unsigned int uint32;
typedef __attribute__((ext_vector_type(8))) short short8;
typedef __attribute__((ext_vector_type(4))) float f32x4;
typedef __attribute__((ext_vector_type(4))) int int4v;

__device__ __forceinline__ ushort_t f2bf(float f) {
  uint32 u = __builtin_bit_cast(uint32, f);
  u = (u + 0x7fffu + ((u >> 16) & 1u)) >> 16;
  return (ushort_t)u;
}

__device__ __forceinline__ float fast_exp2(float x) {
#if __has_builtin(__builtin_amdgcn_exp2f)
  return __builtin_amdgcn_exp2f(x);
#else
  return exp2f(x);
#endif
}

__device__ __forceinline__ void gload_lds16(const void* g, void* l) {
  __builtin_amdgcn_global_load_lds(
      (const __attribute__((address_space(1))) void*)g,
      (__attribute__((address_space(3))) void*)l, 16, 0, 0);
}

#define MFMA16(a, b, c) __builtin_amdgcn_mfma_f32_16x16x32_bf16((a), (b), (c), 0, 0, 0)

// ---------------- fused f32->bf16 conversion of x,Wq,Wk,Wv + mask bias ----------------
__global__ void cvt_all(const float* __restrict__ x, const float* __restrict__ Wq,
                        const float* __restrict__ Wk, const float* __restrict__ Wv,
                        const int* __restrict__ mask, ushort_t* __restrict__ xb,
                        ushort_t* __restrict__ wqk, ushort_t* __restrict__ wv,
                        float* __restrict__ mbias) {
  int i = blockIdx.x * 256 + threadIdx.x;  // group of 8 elements
  if (i >= 1441792) {
    int off = (i - 1441792) * 8;
    if (off < 8192) {
      int4v m0 = *(const int4v*)(mask + off);
      int4v m1 = *(const int4v*)(mask + off + 4);
      f32x4 b0, b1;
      b0.x = m0.x ? 0.f : -30000.f; b0.y = m0.y ? 0.f : -30000.f;
      b0.z = m0.z ? 0.f : -30000.f; b0.w = m0.w ? 0.f : -30000.f;
      b1.x = m1.x ? 0.f : -30000.f; b1.y = m1.y ? 0.f : -30000.f;
      b1.z = m1.z ? 0.f : -30000.f; b1.w = m1.w ? 0.f : -30000.f;
      *(f32x4*)(mbias + off) = b0;
      *(f32x4*)(mbias + off + 4) = b1;
    }
    return;
  }
  const float* src;
  ushort_t* dst;
  int off;
  if (i < 1048576) {
    src = x; dst = xb; off = i;
  } else if (i < 1048576 + 131072) {
    src = Wq; dst = wqk; off = i - 1048576;
  } else if (i < 1048576 + 262144) {
    src = Wk; dst = wqk + 1048576; off = i - (1048576 + 131072);
  } else {
    src = Wv; dst = wv; off = i - (1048576 + 262144);
  }
  const f32x4* s4 = (const f32x4*)src;
  f32x4 a = s4[2 * off], b = s4[2 * off + 1];
  short8 o;
  o[0] = (short)f2bf(a.x); o[1] = (short)f2bf(a.y); o[2] = (short)f2bf(a.z); o[3] = (short)f2bf(a.w);
  o[4] = (short)f2bf(b.x); o[5] = (short)f2bf(b.y); o[6] = (short)f2bf(b.z); o[7] = (short)f2bf(b.w);
  *(short8*)(dst + 8 * off) = o;
}

// ---------------- fused Q+K projection GEMM, 2-phase double-buffered ----------------
// A: xb [8192][1024], Bt: wqk [2048][1024]. col<1024 -> Q (scaled), else K.
// out [bh][s][d] bf16.
__global__ __launch_bounds__(256, 2) void gemm_qk(const ushort_t* __restrict__ A,
                                                  const ushort_t* __restrict__ Bt,
                                                  const float* __restrict__ bq,
                                                  const float* __restrict__ bk,
                                                  ushort_t* __restrict__ Qb,
                                                  ushort_t* __restrict__ Kb, float qscale) {
  __shared__ ushort_t As[2][128 * 32];
  __shared__ ushort_t Bs[2][128 * 32];
  const int K = 1024;
  const int tid = threadIdx.x;
  const int w = tid >> 6, l = tid & 63;
  const int wr = w >> 1, wc = w & 1;
  const int lr = l & 15, g = l >> 4;
  const int bm = blockIdx.y * 128, bn = blockIdx.x * 128;
  const bool isq = bn < 1024;

  const char* gA = (const char*)(A + (size_t)(bm + w * 32 + (l >> 2)) * K + (l & 3) * 8);
  const char* gB = (const char*)(Bt + (size_t)(bn + w * 32 + (l >> 2)) * K + (l & 3) * 8);
  const size_t rowstep = (size_t)16 * K * 2;

  f32x4 acc[4][4] = {};

  auto stage = [&](int buf, int k0) {
    char* dA = (char*)&As[buf][0] + w * 2048;
    char* dB = (char*)&Bs[buf][0] + w * 2048;
    const char* sA = gA + (size_t)k0 * 2;
    const char* sB = gB + (size_t)k0 * 2;
    gload_lds16(sA, dA);
    gload_lds16(sA + rowstep, dA + 1024);
    gload_lds16(sB, dB);
    gload_lds16(sB + rowstep, dB + 1024);
  };

  stage(0, 0);
  __syncthreads();

  const int nk = K >> 5;
  for (int kk = 0; kk < nk; kk++) {
    const int cur = kk & 1;
    if (kk + 1 < nk) stage(cur ^ 1, (kk + 1) << 5);
    short8 af[4], bf[4];
#pragma unroll
    for (int fm = 0; fm < 4; fm++)
      af[fm] = *(const short8*)(&As[cur][(wr * 64 + fm * 16 + lr) * 32 + g * 8]);
#pragma unroll
    for (int fn = 0; fn < 4; fn++)
      bf[fn] = *(const short8*)(&Bs[cur][(wc * 64 + fn * 16 + lr) * 32 + g * 8]);
#pragma unroll
    for (int fm = 0; fm < 4; fm++)
#pragma unroll
      for (int fn = 0; fn < 4; fn++) acc[fm][fn] = MFMA16(af[fm], bf[fn], acc[fm][fn]);
    __syncthreads();
  }

  const float* bias = isq ? bq : bk;
  ushort_t* C = isq ? Qb : Kb;
  const float scale = isq ? qscale : 1.0f;
#pragma unroll
  for (int fn = 0; fn < 4; fn++) {
    int col = bn + wc * 64 + fn * 16 + lr;
    int colh = col & 1023;
    float bv = bias[colh];
    int h = colh >> 6, d = colh & 63;
#pragma unroll
    for (int fm = 0; fm < 4; fm++) {
      int rowb = bm + wr * 64 + fm * 16 + g * 4;
#pragma unroll
      for (int j = 0; j < 4; j++) {
        int row = rowb + j;
        int b = row >> 11, s = row & 2047;
        float v = (acc[fm][fn][j] + bv) * scale;
        C[((size_t)(b * 16 + h) * 2048 + s) * 64 + d] = f2bf(v);
      }
    }
  }
}

// ---------------- V projection GEMM, f32 output ----------------
// A: xb [8192][1024], Bt: wvb [1024][1024]. C f32 row-major [8192][1024] (= V[b,s,h,d]).
__global__ __launch_bounds__(256, 2) void gemm_vf(const ushort_t* __restrict__ A,
                                                  const ushort_t* __restrict__ Bt,
                                                  const float* __restrict__ bias,
                                                  float* __restrict__ C) {
  __shared__ ushort_t As[2][128 * 32];
  __shared__ ushort_t Bs[2][128 * 32];
  const int K = 1024;
  const int tid = threadIdx.x;
  const int w = tid >> 6, l = tid & 63;
  const int wr = w >> 1, wc = w & 1;
  const int lr = l & 15, g = l >> 4;
  const int bm = blockIdx.y * 128, bn = blockIdx.x * 128;

  const char* gA = (const char*)(A + (size_t)(bm + w * 32 + (l >> 2)) * K + (l & 3) * 8);
  const char* gB = (const char*)(Bt + (size_t)(bn + w * 32 + (l >> 2)) * K + (l & 3) * 8);
  const size_t rowstep = (size_t)16 * K * 2;

  f32x4 acc[4][4] = {};

  auto stage = [&](int buf, int k0) {
    char* dA = (char*)&As[buf][0] + w * 2048;
    char* dB = (char*)&Bs[buf][0] + w * 2048;
    const char* sA = gA + (size_t)k0 * 2;
    const char* sB = gB + (size_t)k0 * 2;
    gload_lds16(sA, dA);
    gload_lds16(sA + rowstep, dA + 1024);
    gload_lds16(sB, dB);
    gload_lds16(sB + rowstep, dB + 1024);
  };

  stage(0, 0);
  __syncthreads();

  const int nk = K >> 5;
  for (int kk = 0; kk < nk; kk++) {
    const int cur = kk & 1;
    if (kk + 1 < nk) stage(cur ^ 1, (kk + 1) << 5);
    short8 af[4], bf[4];
#pragma unroll
    for (int fm = 0; fm < 4; fm++)
      af[fm] = *(const short8*)(&As[cur][(wr * 64 + fm * 16 + lr) * 32 + g * 8]);
#pragma unroll
    for (int fn = 0; fn < 4; fn++)
      bf[fn] = *(const short8*)(&Bs[cur][(wc * 64 + fn * 16 + lr) * 32 + g * 8]);
#pragma unroll
    for (int fm = 0; fm < 4; fm++)
#pragma unroll
      for (int fn = 0; fn < 4; fn++) acc[fm][fn] = MFMA16(af[fm], bf[fn], acc[fm][fn]);
    __syncthreads();
  }

#pragma unroll
  for (int fn = 0; fn < 4; fn++) {
    int col = bn + wc * 64 + fn * 16 + lr;
    float bv = bias[col];
#pragma unroll
    for (int fm = 0; fm < 4; fm++) {
      int rowb = bm + wr * 64 + fm * 16 + g * 4;
#pragma unroll
      for (int j = 0; j < 4; j++) {
        C[(size_t)(rowb + j) * 1024 + col] = acc[fm][fn][j] + bv;
      }
    }
  }
}

// ---------------- pass 1: per-q softmax normalizer c_q = m + log2(sum) ----------------
// Q pre-scaled by log2(e)/8; scores in log2 domain.
__global__ __launch_bounds__(256, 4) void qk_stats(const ushort_t* __restrict__ Qb,
                                                   const ushort_t* __restrict__ Kb,
                                                   const float* __restrict__ mbias,
                                                   float* __restrict__ cq) {
  __shared__ ushort_t Ks[2][64 * 64];
  const int tid = threadIdx.x;
  const int w = tid >> 6, l = tid & 63;
  const int g = l >> 4, qi = l & 15;
  const int xr = qi & 7;
  const int qblk = blockIdx.x, bh = blockIdx.y;
  const int b = bh >> 4;
  const int q0 = qblk * 128 + w * 32;

  short8 qf[2][2];
#pragma unroll
  for (int qh = 0; qh < 2; qh++) {
    const ushort_t* qp = Qb + ((size_t)bh * 2048 + q0 + qh * 16 + qi) * 64 + g * 8;
    qf[qh][0] = *(const short8*)qp;
    qf[qh][1] = *(const short8*)(qp + 32);
  }

  const int srow = l >> 3;
  const int sch = (l & 7) ^ srow;
  const char* gK = (const char*)Kb + ((size_t)bh * 2048 + w * 8 + srow) * 128 + sch * 16;
  const float* bbase = mbias + b * 2048 + g * 4;

  auto stage = [&](int buf, int t) {
    const char* sK = gK + (size_t)t * (64 * 128);
    char* dK = (char*)&Ks[buf][0] + w * 1024;
    gload_lds16(sK, dK);
    gload_lds16(sK + 32 * 128, dK + 4096);
  };

  float mrun[2] = {-1e30f, -1e30f}, lsum[2] = {0.f, 0.f};
  stage(0, 0);
  __syncthreads();

  for (int t = 0; t < 32; t++) {
    const int cur = t & 1;
    f32x4 bvec[4];
#pragma unroll
    for (int fn = 0; fn < 4; fn++) bvec[fn] = *(const f32x4*)(bbase + t * 64 + fn * 16);

    if (t < 31) stage(cur ^ 1, t + 1);

    short8 kf[4][2];
#pragma unroll
    for (int fn = 0; fn < 4; fn++) {
      const ushort_t* kr = &Ks[cur][(fn * 16 + qi) * 64];
      kf[fn][0] = *(const short8*)(kr + (g ^ xr) * 8);
      kf[fn][1] = *(const short8*)(kr + ((4 + g) ^ xr) * 8);
    }

#pragma unroll
    for (int qh = 0; qh < 2; qh++) {
      f32x4 sc[4];
#pragma unroll
      for (int fn = 0; fn < 4; fn++) {
        f32x4 z = {};
        z = MFMA16(kf[fn][0], qf[qh][0], z);
        z = MFMA16(kf[fn][1], qf[qh][1], z);
        sc[fn] = z;
      }
      float pmax = -1e30f;
#pragma unroll
      for (int fn = 0; fn < 4; fn++)
#pragma unroll
        for (int j = 0; j < 4; j++) {
          float v = sc[fn][j] + bvec[fn][j];
          sc[fn][j] = v;
          pmax = fmaxf(pmax, v);
        }
      pmax = fmaxf(pmax, __shfl_xor(pmax, 16));
      pmax = fmaxf(pmax, __shfl_xor(pmax, 32));
      if (__any(pmax > mrun[qh] + 8.f)) {
        float mnew = fmaxf(mrun[qh], pmax);
        lsum[qh] *= fast_exp2(mrun[qh] - mnew);
        mrun[qh] = mnew;
      }
      const float m = mrun[qh];
      float psum = 0.f;
#pragma unroll
      for (int fn = 0; fn < 4; fn++) {
        float p0 = fast_exp2(sc[fn][0] - m);
        float p1 = fast_exp2(sc[fn][1] - m);
        float p2 = fast_exp2(sc[fn][2] - m);
        float p3 = fast_exp2(sc[fn][3] - m);
        psum += (p0 + p1) + (p2 + p3);
      }
      psum += __shfl_xor(psum, 16);
      psum += __shfl_xor(psum, 32);
      lsum[qh] += psum;
    }
    __syncthreads();
  }

#pragma unroll
  for (int qh = 0; qh < 2; qh++)
    if (l < 16) cq[(size_t)bh * 2048 + q0 + qh * 16 + l] = mrun[qh] + __log2f(lsum[qh]);
}

// ---------------- pass 2: w_k = sum_q 2^(s_kq - c_q); meanO += V^T w (f32) ----------------
__global__ __launch_bounds__(256, 3) void wsum_v(const ushort_t* __restrict__ Qb,
                                                 const ushort_t* __restrict__ Kb,
                                                 const float* __restrict__ Vf,
                                                 const float* __restrict__ mbias,
                                                 const float* __restrict__ cq,
                                                 float* __restrict__ meanO) {
  __shared__ ushort_t Qs[2][64 * 64];
  __shared__ float wl[4][64];
  const int tid = threadIdx.x;
  const int w = tid >> 6, l = tid & 63;
  const int g = l >> 4, qi = l & 15;
  const int xr = qi & 7;
  const int kvb = blockIdx.x, bh = blockIdx.y;
  const int b = bh >> 4, h = bh & 15;
  const int kv0 = kvb * 256 + w * 64;  // wave's kv base within bh

  // persistent K fragments for this wave's 64 kv rows
  short8 kf[4][2];
#pragma unroll
  for (int fn = 0; fn < 4; fn++) {
    const ushort_t* kp = Kb + ((size_t)bh * 2048 + kv0 + fn * 16 + qi) * 64 + g * 8;
    kf[fn][0] = *(const short8*)kp;
    kf[fn][1] = *(const short8*)(kp + 32);
  }
  f32x4 bvec[4];
#pragma unroll
  for (int fn = 0; fn < 4; fn++)
    bvec[fn] = *(const f32x4*)(mbias + b * 2048 + kv0 + fn * 16 + g * 4);

  const int srow = l >> 3, sch = (l & 7) ^ srow;
  const char* gQ = (const char*)Qb + ((size_t)bh * 2048 + w * 8 + srow) * 128 + sch * 16;
  auto stageQ = [&](int buf, int t) {
    const char* sQ = gQ + (size_t)t * (64 * 128);
    char* dQ = (char*)&Qs[buf][0] + w * 1024;
    gload_lds16(sQ, dQ);
    gload_lds16(sQ + 32 * 128, dQ + 4096);
  };

  f32x4 acc[4] = {};
  const float* cqb = cq + (size_t)bh * 2048;
  stageQ(0, 0);
  __syncthreads();

  for (int t = 0; t < 32; t++) {
    const int cur = t & 1;
    if (t < 31) stageQ(cur ^ 1, t + 1);
#pragma unroll
    for (int sub = 0; sub < 4; sub++) {
      const ushort_t* qr = &Qs[cur][(sub * 16 + qi) * 64];
      short8 q0f = *(const short8*)(qr + (g ^ xr) * 8);
      short8 q1f = *(const short8*)(qr + ((4 + g) ^ xr) * 8);
      float cv = cqb[t * 64 + sub * 16 + qi];
#pragma unroll
      for (int fn = 0; fn < 4; fn++) {
        f32x4 z = {};
        z = MFMA16(kf[fn][0], q0f, z);
        z = MFMA16(kf[fn][1], q1f, z);
#pragma unroll
        for (int j = 0; j < 4; j++) acc[fn][j] += fast_exp2(z[j] + bvec[fn][j] - cv);
      }
    }
    __syncthreads();
  }

  // reduce over the 16 q-lanes (lane bits 0..3)
#pragma unroll
  for (int msk = 1; msk < 16; msk <<= 1) {
#pragma unroll
    for (int fn = 0; fn < 4; fn++) {
      acc[fn][0] += __shfl_xor(acc[fn][0], msk);
      acc[fn][1] += __shfl_xor(acc[fn][1], msk);
      acc[fn][2] += __shfl_xor(acc[fn][2], msk);
      acc[fn][3] += __shfl_xor(acc[fn][3], msk);
    }
  }
  if (qi == 0) {
#pragma unroll
    for (int fn = 0; fn < 4; fn++)
#pragma unroll
      for (int j = 0; j < 4; j++) wl[w][fn * 16 + g * 4 + j] = acc[fn][j];
  }
  __syncthreads();

  // f32 V contraction: lane l = d
  float od = 0.f;
  const float* vrow = Vf + (size_t)(b * 2048 + kv0) * 1024 + h * 64 + l;
  const float* wp = wl[w];
#pragma unroll 8
  for (int k = 0; k < 64; k++) od += wp[k] * vrow[(size_t)k * 1024];
  atomicAdd(&meanO[b * 1024 + h * 64 + l], od);
}

// ---------------- y[b][n] = (meanO[b]/S) . Wo[n] + bo[n] ----------------
__global__ void proj_o(const float* __restrict__ meanO, const float* __restrict__ Wo,
                       const float* __restrict__ bo, float* __restrict__ y) {
  int b = blockIdx.y;
  int t = threadIdx.x;
  int n = blockIdx.x * 64 + (t >> 2);
  int part = t & 3;
  const f32x4* wrow = (const f32x4*)(Wo + (size_t)n * 1024 + part * 256);
  const f32x4* mo = (const f32x4*)(meanO + b * 1024 + part * 256);
  float acc = 0.f;
#pragma unroll 8
  for (int i = 0; i < 64; i++) {
    f32x4 wv = wrow[i], mv = mo[i];
    acc += wv.x * mv.x + wv.y * mv.y + wv.z * mv.z + wv.w * mv.w;
  }
  acc += __shfl_xor(acc, 1);
  acc += __shfl_xor(acc, 2);
  if (part == 0) y[b * 1024 + n] = acc * (1.0f / 2048.0f) + bo[n];
}

// ---------------- norm + subtract text ----------------
__global__ void norm_kernel(const float* __restrict__ y, const float* __restrict__ text,
                            float* __restrict__ u) {
  __shared__ float red[4];
  int b = blockIdx.x, t = threadIdx.x;
  const float* yb = y + b * 1024;
  float ss = 0.f;
  for (int i = t; i < 1024; i += 256) {
    float v = yb[i];
    ss += v * v;
  }
  for (int m = 1; m < 64; m <<= 1) ss += __shfl_xor(ss, m);
  if ((t & 63) == 0) red[t >> 6] = ss;
  __syncthreads();
  float rn = rsqrtf(red[0] + red[1] + red[2] + red[3]);
  for (int i = t; i < 1024; i += 256) u[b * 1024 + i] = yb[i] * rn - text[b * 1024 + i];
}

// ---------------- MLP layer 1: h = relu(u @ W1^T + b1), parallel over j-blocks ----------------
__global__ void mlp1_kernel(const float* __restrict__ u, const float* __restrict__ W1,
                            const float* __restrict__ b1, float* __restrict__ hb) {
  int b = blockIdx.y;
  int t = threadIdx.x;
  int j = blockIdx.x * 64 + (t >> 2);
  int part = t & 3;
  const f32x4* wr = (const f32x4*)(W1 + (size_t)j * 1024 + part * 256);
  const f32x4* uu = (const f32x4*)(u + b * 1024 + part * 256);
  float a = 0.f;
#pragma unroll 8
  for (int i = 0; i < 64; i++) {
    f32x4 wv = wr[i], uv = uu[i];
    a += wv.x * uv.x + wv.y * uv.y + wv.z * uv.z + wv.w * uv.w;
  }
  a += __shfl_xor(a, 1);
  a += __shfl_xor(a, 2);
  if (part == 0) hb[b * 512 + j] = fmaxf(a + b1[j], 0.f);
}

// ---------------- MLP layer 2 + tanh ----------------
__global__ void mlp2_kernel(const float* __restrict__ hb, const float* __restrict__ W2,
                            const float* __restrict__ b2, float* __restrict__ out) {
  __shared__ float red[4];
  int b = blockIdx.x, t = threadIdx.x;
  float s2 = 0.f;
  for (int j = t; j < 512; j += 256) s2 += hb[b * 512 + j] * W2[j];
  for (int m = 1; m < 64; m <<= 1) s2 += __shfl_xor(s2, m);
  if ((t & 63) == 0) red[t >> 6] = s2;
  __syncthreads();
  if (t == 0) out[b] = tanhf(red[0] + red[1] + red[2] + red[3] + b2[0]);
}

extern "C" void kernel_launch(void* const* d_in, const int* in_sizes, int n_in, void* d_out,
                              int out_size, void* d_ws, size_t ws_size, hipStream_t stream) {
  (void)in_sizes; (void)n_in; (void)out_size; (void)ws_size;
  const float* x = (const float*)d_in[0];
  const int* mask = (const int*)d_in[1];
  const float* text = (const float*)d_in[2];
  const float* Wq = (const float*)d_in[3];
  const float* bq = (const float*)d_in[4];
  const float* Wk = (const float*)d_in[5];
  const float* bk = (const float*)d_in[6];
  const float* Wv = (const float*)d_in[7];
  const float* bv = (const float*)d_in[8];
  const float* Wo = (const float*)d_in[9];
  const float* bo = (const float*)d_in[10];
  const float* W1 = (const float*)d_in[11];
  const float* b1 = (const float*)d_in[12];
  const float* W2 = (const float*)d_in[13];
  const float* b2 = (const float*)d_in[14];

  char* ws = (char*)d_ws;
  const size_t MB = 1024 * 1024;
  ushort_t* Qb = (ushort_t*)(ws);             // 16 MB  [bh][s][d] bf16
  ushort_t* Kb = (ushort_t*)(ws + 16 * MB);   // 16 MB  [bh][s][d] bf16
  float* Vf = (float*)(ws + 32 * MB);         // 32 MB  [b*2048+s][h*64+d] f32
  ushort_t* xb = (ushort_t*)(ws + 64 * MB);   // 16 MB
  ushort_t* wqk = (ushort_t*)(ws + 80 * MB);  // 4 MB   [2048][1024] Wq then Wk
  ushort_t* wvb = (ushort_t*)(ws + 84 * MB);  // 2 MB
  float* cq = (float*)(ws + 86 * MB);         // 512 KB [bh][2048]
  float* meanO = (float*)(ws + 87 * MB);      // 16 KB
  float* y = (float*)(ws + 87 * MB + 16384);
  float* u = (float*)(ws + 87 * MB + 32768);
  float* hb = (float*)(ws + 87 * MB + 49152);
  float* mbias = (float*)(ws + 87 * MB + 65536);

  cvt_all<<<5636, 256, 0, stream>>>(x, Wq, Wk, Wv, mask, xb, wqk, wvb, mbias);
  hipMemsetAsync(meanO, 0, 4096 * sizeof(float), stream);

  // Q = x @ Wq^T (scaled by log2(e)/sqrt(D)) and K = x @ Wk^T, fused: [bh][s][d]
  const float qscale = 0.125f * 1.44269504088896f;
  gemm_qk<<<dim3(16, 64), 256, 0, stream>>>(xb, wqk, bq, bk, Qb, Kb, qscale);
  // V = x @ Wv^T + bv, f32 row-major [8192][1024]
  gemm_vf<<<dim3(8, 64), 256, 0, stream>>>(xb, wvb, bv, Vf);

  qk_stats<<<dim3(16, 64), 256, 0, stream>>>(Qb, Kb, mbias, cq);
  wsum_v<<<dim3(8, 64), 256, 0, stream>>>(Qb, Kb, Vf, mbias, cq, meanO);

  proj_o<<<dim3(16, 4), 256, 0, stream>>>(meanO, Wo, bo, y);
  norm_kernel<<<4, 256, 0, stream>>>(y, text, u);
  mlp1_kernel<<<dim3(8, 4), 256, 0, stream>>>(u, W1, b1, hb);
  mlp2_kernel<<<4, 256, 0, stream>>>(hb, W2, b2, (float*)d_out);
}